// Round 10
// baseline (384.580 us; speedup 1.0000x reference)
//
#include <hip/hip_runtime.h>
#include <hip/hip_bf16.h>

#define BB 4
#define CC 256
#define NN 4096
#define SS 3
#define C8 32
#define L2E 1.4426950408889634f

typedef __attribute__((ext_vector_type(8))) short short8;
typedef __attribute__((ext_vector_type(4))) float floatx4;

static __device__ inline unsigned pack_bf16(float a, float b) {
  union { __hip_bfloat16 h; unsigned short u; } ua, ub;
  ua.h = __float2bfloat16(a);
  ub.h = __float2bfloat16(b);
  return ((unsigned)ub.u << 16) | (unsigned)ua.u;
}

// hardware packed convert: one v_cvt_pk_bf16_f32 (RNE) per pair
static __device__ inline unsigned cvt_pk_bf16(float a, float b) {
  union { __hip_bfloat162 h2; unsigned u; } cv;
  cv.h2 = __float22bfloat162_rn(make_float2(a, b));
  return cv.u;
}

static __device__ inline float fast_exp2(float x) {
#if __has_builtin(__builtin_amdgcn_exp2f)
  return __builtin_amdgcn_exp2f(x);
#else
  return exp2f(x);
#endif
}

// ---------------------------------------------------------------------------
// P0: weight fp32->bf16 convert (832 blocks, ~4us). Must precede fused_in.
// ---------------------------------------------------------------------------
__global__ void __launch_bounds__(256) wconv_kernel(
    const float* __restrict__ Wq, const float* __restrict__ Wk,
    const float* __restrict__ Wv, const float* __restrict__ Wf,
    __hip_bfloat16* __restrict__ WqB, __hip_bfloat16* __restrict__ WkB,
    __hip_bfloat16* __restrict__ WvB, __hip_bfloat16* __restrict__ WfB) {
  int idx = blockIdx.x * 256 + threadIdx.x;
  if (idx < 8192) WqB[idx] = __float2bfloat16(Wq[idx] * L2E);
  else if (idx < 16384) WkB[idx - 8192] = __float2bfloat16(Wk[idx - 8192]);
  else if (idx < 81920) WvB[idx - 16384] = __float2bfloat16(Wv[idx - 16384]);
  else if (idx < 212992) WfB[idx - 81920] = __float2bfloat16(Wf[idx - 81920]);
}

// ---------------------------------------------------------------------------
// F1: fused transpose + projection. Grid (64 n-tiles, 16 z).
// z<12 (x_b plane g=z):  stage 64n x 256c tile -> swizzled bf16 LDS, then
//   V-proj (vB[g][o][n] = Wv @ tile + bv) and Q-proj (qT[g][n][32]).
// z>=12 (x_f plane g=z-12): stage tile, write xfT (needed by final), K-proj.
// xbT intermediate ELIMINATED (was 24MB written + 48MB read through L2/L3).
// LDS tile swizzle = attn's proven pattern: 16B chunk ^= (row&7); b128 reads
// 2-way (free), staging writes 2-way (free).
// ---------------------------------------------------------------------------
__global__ void __launch_bounds__(256) fused_in_kernel(
    const float* __restrict__ xb, const float* __restrict__ xf,
    const __hip_bfloat16* __restrict__ WqB, const __hip_bfloat16* __restrict__ WkB,
    const __hip_bfloat16* __restrict__ WvB,
    const float* __restrict__ bq, const float* __restrict__ bk,
    const float* __restrict__ bv,
    __hip_bfloat16* __restrict__ qT, __hip_bfloat16* __restrict__ kT,
    __hip_bfloat16* __restrict__ vB, __hip_bfloat16* __restrict__ xfT) {
  __shared__ float ts[64][65];
  __shared__ char xs[64 * 512];  // bf16 [64 n][256 c], 16B-chunk XOR swizzle
  const int z = blockIdx.y;
  const bool isb = (z < 12);
  const int g = isb ? z : z - 12;
  const int n0 = blockIdx.x * 64;
  const int t = threadIdx.x, w = t >> 6, lane = t & 63;
  const int q = lane >> 4, li = lane & 15;
  const float* X = (isb ? xb : xf) + (size_t)g * CC * NN + n0;
  __hip_bfloat16* xout = xfT + (size_t)g * NN * CC + (size_t)n0 * CC;

  // stage: 4 c-chunks of 64: fp32 transpose staging -> packed bf16 tile
  for (int cc = 0; cc < 4; ++cc) {
    const float* Xg = X + (size_t)(cc * 64) * NN;
    for (int idx = t; idx < 64 * 64; idx += 256) {
      int r = idx >> 6, nn = idx & 63;
      ts[r][nn] = Xg[(size_t)r * NN + nn];
    }
    __syncthreads();
    for (int idx = t; idx < 64 * 32; idx += 256) {
      int nn = idx >> 5, pc = idx & 31;  // pc = dword within this c-chunk
      unsigned pv = cvt_pk_bf16(ts[2 * pc][nn], ts[2 * pc + 1][nn]);
      int d = cc * 32 + pc;              // dword index within row, 0..127
      int chunk = (d >> 2) ^ (nn & 7);
      ((unsigned*)(xs + nn * 512 + chunk * 16))[d & 3] = pv;
      if (!isb) ((unsigned*)(xout + (size_t)nn * CC))[d] = pv;
    }
    __syncthreads();
  }

  floatx4 zf = {0.f, 0.f, 0.f, 0.f};
  if (isb) {
    // ---- V projection: wave w owns o-quarter w*64, nt=0..3 over the n-tile
    const int o_w = w * 64;
    __hip_bfloat16* dst = vB + (size_t)g * CC * NN;
    floatx4 acc[4][4];
#pragma unroll
    for (int ot = 0; ot < 4; ++ot)
#pragma unroll
      for (int nt = 0; nt < 4; ++nt) acc[ot][nt] = zf;
#pragma unroll
    for (int kc = 0; kc < 8; ++kc) {
      short8 a[4], bfr[4];
#pragma unroll
      for (int ot = 0; ot < 4; ++ot)
        a[ot] = *(const short8*)(WvB + (size_t)(o_w + ot * 16 + li) * CC + kc * 32 + q * 8);
#pragma unroll
      for (int nt = 0; nt < 4; ++nt) {
        int nn = nt * 16 + li;
        int chunk = (kc * 4 + q) ^ (nn & 7);
        bfr[nt] = *(const short8*)(xs + nn * 512 + chunk * 16);
      }
#pragma unroll
      for (int ot = 0; ot < 4; ++ot)
#pragma unroll
        for (int nt = 0; nt < 4; ++nt)
          acc[ot][nt] = __builtin_amdgcn_mfma_f32_16x16x32_bf16(a[ot], bfr[nt],
                                                                acc[ot][nt], 0, 0, 0);
    }
#pragma unroll
    for (int ot = 0; ot < 4; ++ot) {
#pragma unroll
      for (int r = 0; r < 4; ++r) {
        int o = o_w + ot * 16 + q * 4 + r;
        float bo = bv[o];
#pragma unroll
        for (int nt = 0; nt < 4; ++nt)
          dst[(size_t)o * NN + n0 + nt * 16 + li] =
              __float2bfloat16(acc[ot][nt][r] + bo);
      }
    }
    // ---- Q projection: wave w owns n-sub w*16 (16 rows), 32 outputs
    {
      __hip_bfloat16* qdst = qT + (size_t)g * NN * C8;
      const int nn = w * 16 + li;
      floatx4 acc2[2];
      acc2[0] = zf; acc2[1] = zf;
#pragma unroll
      for (int kc = 0; kc < 8; ++kc) {
        short8 a2[2];
#pragma unroll
        for (int ot = 0; ot < 2; ++ot)
          a2[ot] = *(const short8*)(WqB + (size_t)(ot * 16 + li) * CC + kc * 32 + q * 8);
        int chunk = (kc * 4 + q) ^ (nn & 7);
        short8 bfr = *(const short8*)(xs + nn * 512 + chunk * 16);
#pragma unroll
        for (int ot = 0; ot < 2; ++ot)
          acc2[ot] = __builtin_amdgcn_mfma_f32_16x16x32_bf16(a2[ot], bfr, acc2[ot], 0, 0, 0);
      }
#pragma unroll
      for (int ot = 0; ot < 2; ++ot) {
        float bv0 = bq[ot * 16 + q * 4 + 0] * L2E;
        float bv1 = bq[ot * 16 + q * 4 + 1] * L2E;
        float bv2 = bq[ot * 16 + q * 4 + 2] * L2E;
        float bv3 = bq[ot * 16 + q * 4 + 3] * L2E;
        int n = n0 + nn;
        uint2 pk;
        pk.x = pack_bf16(acc2[ot][0] + bv0, acc2[ot][1] + bv1);
        pk.y = pack_bf16(acc2[ot][2] + bv2, acc2[ot][3] + bv3);
        *(uint2*)(qdst + (size_t)n * C8 + ot * 16 + q * 4) = pk;
      }
    }
  } else {
    // ---- K projection: wave w owns n-sub w*16
    __hip_bfloat16* kdst = kT + (size_t)g * NN * C8;
    const int nn = w * 16 + li;
    floatx4 acc2[2];
    acc2[0] = zf; acc2[1] = zf;
#pragma unroll
    for (int kc = 0; kc < 8; ++kc) {
      short8 a2[2];
#pragma unroll
      for (int ot = 0; ot < 2; ++ot)
        a2[ot] = *(const short8*)(WkB + (size_t)(ot * 16 + li) * CC + kc * 32 + q * 8);
      int chunk = (kc * 4 + q) ^ (nn & 7);
      short8 bfr = *(const short8*)(xs + nn * 512 + chunk * 16);
#pragma unroll
      for (int ot = 0; ot < 2; ++ot)
        acc2[ot] = __builtin_amdgcn_mfma_f32_16x16x32_bf16(a2[ot], bfr, acc2[ot], 0, 0, 0);
    }
#pragma unroll
    for (int ot = 0; ot < 2; ++ot) {
      float bv0 = bk[ot * 16 + q * 4 + 0];
      float bv1 = bk[ot * 16 + q * 4 + 1];
      float bv2 = bk[ot * 16 + q * 4 + 2];
      float bv3 = bk[ot * 16 + q * 4 + 3];
      int n = n0 + nn;
      uint2 pk;
      pk.x = pack_bf16(acc2[ot][0] + bv0, acc2[ot][1] + bv1);
      pk.y = pack_bf16(acc2[ot][2] + bv2, acc2[ot][3] + bv3);
      *(uint2*)(kdst + (size_t)n * C8 + ot * 16 + q * 4) = pk;
    }
  }
}

// ---------------------------------------------------------------------------
// K3: MFMA flash attention — proven round-2/9 kernel (213us): 128-j outer
// iter, 4x8KB P buffers, ONE __syncthreads per 128 j, setprio on PV, plain
// stores to per-s fp32 slabs, hw cvt_pk pack. UNCHANGED from round 9.
// ---------------------------------------------------------------------------
__global__ void __launch_bounds__(256) attn_kernel(
    const __hip_bfloat16* __restrict__ qT, const __hip_bfloat16* __restrict__ kT,
    const __hip_bfloat16* __restrict__ vB, float* __restrict__ outs_s) {
  __shared__ uint4 Ps4[4 * 64 * 8];  // 4 x 8KB P buffers, 16B-chunk XOR swizzle
  __shared__ float lsum[64];
  char* Ps0 = (char*)Ps4;
  const int x_ = blockIdx.x;
  const int wk = (x_ & 7) * 96 + (x_ >> 3);  // contiguous range per XCD
  const int g  = wk >> 6;                    // 0..11 (= s*4+b)
  const int i0 = (wk & 63) << 6;
  const int b  = g & 3;
  const int t  = threadIdx.x;
  const int w  = t >> 6;
  const int lane = t & 63, q = lane >> 4, li = lane & 15;

  if (t < 64) lsum[t] = 0.f;

  short8 qf[4];
#pragma unroll
  for (int it = 0; it < 4; ++it)
    qf[it] = *(const short8*)(qT + ((size_t)g * NN + i0 + it * 16 + li) * C8 + q * 8);

  floatx4 acc[4][4];
  floatx4 zf = {0.f, 0.f, 0.f, 0.f};
#pragma unroll
  for (int ct = 0; ct < 4; ++ct)
#pragma unroll
    for (int it = 0; it < 4; ++it) acc[ct][it] = zf;
  float rsum[4] = {0.f, 0.f, 0.f, 0.f};

  const __hip_bfloat16* kb = kT + (size_t)b * NN * C8;
  const __hip_bfloat16* vb = vB + (size_t)g * CC * NN;
  short8 kf0 = *(const short8*)(kb + (size_t)(0 + w * 16 + li) * C8 + q * 8);
  short8 kf1 = *(const short8*)(kb + (size_t)(64 + w * 16 + li) * C8 + q * 8);

  for (int j0 = 0; j0 < NN; j0 += 128) {
    int j0n = (j0 + 128) & (NN - 1);
    char* PsA = Ps0 + ((j0 >> 6) & 2) * 8192;  // pair {0,1} / {2,3} alternates
    char* PsB = PsA + 8192;
    // V frags for subtile A: issue first so L2 latency hides under S/exp work
    short8 vfA[4][2];
#pragma unroll
    for (int ct = 0; ct < 4; ++ct)
#pragma unroll
      for (int kk = 0; kk < 2; ++kk)
        vfA[ct][kk] = *(const short8*)(vb + (size_t)(w * 64 + ct * 16 + li) * NN +
                                       j0 + kk * 32 + q * 8);
    // --- subtile A: S^T strip, exp2, pack, LDS write (stA dies here) ---
    {
      floatx4 stA[4];
#pragma unroll
      for (int it = 0; it < 4; ++it)
        stA[it] = __builtin_amdgcn_mfma_f32_16x16x32_bf16(kf0, qf[it], zf, 0, 0, 0);
      kf0 = *(const short8*)(kb + (size_t)(j0n + w * 16 + li) * C8 + q * 8);
      uint2 pk[4];
#pragma unroll
      for (int it = 0; it < 4; ++it) {
        float e0 = fast_exp2(stA[it][0]), e1 = fast_exp2(stA[it][1]);
        float e2 = fast_exp2(stA[it][2]), e3 = fast_exp2(stA[it][3]);
        rsum[it] += (e0 + e1) + (e2 + e3);
        pk[it].x = cvt_pk_bf16(e0, e1);
        pk[it].y = cvt_pk_bf16(e2, e3);
      }
#pragma unroll
      for (int it = 0; it < 4; ++it) {
        int row = it * 16 + li;
        int chunk = (w * 2 + (q >> 1)) ^ (row & 7);
        *(uint2*)(PsA + row * 128 + chunk * 16 + (q & 1) * 8) = pk[it];
      }
    }
    // --- subtile B: S^T strip, exp2, pack, LDS write ---
    {
      floatx4 stB[4];
#pragma unroll
      for (int it = 0; it < 4; ++it)
        stB[it] = __builtin_amdgcn_mfma_f32_16x16x32_bf16(kf1, qf[it], zf, 0, 0, 0);
      kf1 = *(const short8*)(kb + (size_t)(j0n + 64 + w * 16 + li) * C8 + q * 8);
      uint2 pk[4];
#pragma unroll
      for (int it = 0; it < 4; ++it) {
        float e0 = fast_exp2(stB[it][0]), e1 = fast_exp2(stB[it][1]);
        float e2 = fast_exp2(stB[it][2]), e3 = fast_exp2(stB[it][3]);
        rsum[it] += (e0 + e1) + (e2 + e3);
        pk[it].x = cvt_pk_bf16(e0, e1);
        pk[it].y = cvt_pk_bf16(e2, e3);
      }
#pragma unroll
      for (int it = 0; it < 4; ++it) {
        int row = it * 16 + li;
        int chunk = (w * 2 + (q >> 1)) ^ (row & 7);
        *(uint2*)(PsB + row * 128 + chunk * 16 + (q & 1) * 8) = pk[it];
      }
    }
    __syncthreads();  // one barrier per 128 j; alternating pairs make reads safe
    // --- PV subtile A (vfA dies here) ---
    __builtin_amdgcn_s_setprio(1);
#pragma unroll
    for (int kk = 0; kk < 2; ++kk) {
      short8 pf[4];
#pragma unroll
      for (int it = 0; it < 4; ++it) {
        int row = it * 16 + li;
        int chunk = (kk * 4 + q) ^ (row & 7);
        pf[it] = *(const short8*)(PsA + row * 128 + chunk * 16);
      }
#pragma unroll
      for (int ct = 0; ct < 4; ++ct)
#pragma unroll
        for (int it = 0; it < 4; ++it)
          acc[ct][it] = __builtin_amdgcn_mfma_f32_16x16x32_bf16(
              vfA[ct][kk], pf[it], acc[ct][it], 0, 0, 0);
    }
    __builtin_amdgcn_s_setprio(0);
    // V frags for subtile B (vfA dead -> regs reuse)
    short8 vfB[4][2];
#pragma unroll
    for (int ct = 0; ct < 4; ++ct)
#pragma unroll
      for (int kk = 0; kk < 2; ++kk)
        vfB[ct][kk] = *(const short8*)(vb + (size_t)(w * 64 + ct * 16 + li) * NN +
                                       j0 + 64 + kk * 32 + q * 8);
    // --- PV subtile B ---
    __builtin_amdgcn_s_setprio(1);
#pragma unroll
    for (int kk = 0; kk < 2; ++kk) {
      short8 pf[4];
#pragma unroll
      for (int it = 0; it < 4; ++it) {
        int row = it * 16 + li;
        int chunk = (kk * 4 + q) ^ (row & 7);
        pf[it] = *(const short8*)(PsB + row * 128 + chunk * 16);
      }
#pragma unroll
      for (int ct = 0; ct < 4; ++ct)
#pragma unroll
        for (int it = 0; it < 4; ++it)
          acc[ct][it] = __builtin_amdgcn_mfma_f32_16x16x32_bf16(
              vfB[ct][kk], pf[it], acc[ct][it], 0, 0, 0);
    }
    __builtin_amdgcn_s_setprio(0);
  }
#pragma unroll
  for (int it = 0; it < 4; ++it) {
    float v = rsum[it];
    v += __shfl_xor(v, 16, 64);
    v += __shfl_xor(v, 32, 64);
    if (lane < 16) atomicAdd(&lsum[it * 16 + li], v);
  }
  __syncthreads();
  float inv[4];
#pragma unroll
  for (int it = 0; it < 4; ++it) inv[it] = 1.0f / lsum[it * 16 + li];
  float* ob = outs_s + (size_t)g * CC * NN + i0;
#pragma unroll
  for (int ct = 0; ct < 4; ++ct)
#pragma unroll
    for (int it = 0; it < 4; ++it)
#pragma unroll
      for (int r = 0; r < 4; ++r) {
        int c = w * 64 + ct * 16 + q * 4 + r;
        ob[(size_t)c * NN + it * 16 + li] = acc[ct][it][r] * inv[it];
      }
}

// ---------------------------------------------------------------------------
// G3: final projection with T2 fused (3-way s-sum + gamma + transpose staged
// through LDS), n-tile 32, grid (128, 4). UNCHANGED from round 9.
// ---------------------------------------------------------------------------
__global__ void __launch_bounds__(256) final_kernel(
    const float* __restrict__ outs_s, const __hip_bfloat16* __restrict__ xfT,
    const __hip_bfloat16* __restrict__ WfB, const float* __restrict__ bfv,
    const float* __restrict__ gp, float* __restrict__ out) {
  __shared__ float ts[64][33];
  __shared__ __hip_bfloat16 Pn[32][280];
  const int b = blockIdx.y, n0 = blockIdx.x * 32;
  const int t = threadIdx.x, w = t >> 6, lane = t & 63;
  const int q = lane >> 4, li = lane & 15;
  const float sc = gp[0];
  for (int cc = 0; cc < 4; ++cc) {
    const int c0 = cc * 64;
    const float* X0 = outs_s + ((size_t)(0 + b) * CC + c0) * NN + n0;
    const float* X1 = outs_s + ((size_t)(4 + b) * CC + c0) * NN + n0;
    const float* X2 = outs_s + ((size_t)(8 + b) * CC + c0) * NN + n0;
    for (int idx = t; idx < 64 * 32; idx += 256) {
      int r = idx >> 5, col = idx & 31;
      size_t off = (size_t)r * NN + col;
      ts[r][col] = X0[off] + X1[off] + X2[off];
    }
    __syncthreads();
    for (int idx = t; idx < 32 * 32; idx += 256) {
      int n = idx >> 5, pc = idx & 31;
      ((unsigned*)&Pn[n][c0])[pc] =
          pack_bf16(ts[2 * pc][n] * sc, ts[2 * pc + 1][n] * sc);
    }
    __syncthreads();
  }
  const __hip_bfloat16* xT = xfT + (size_t)b * NN * CC;
  const int o_w = w * 64;
  floatx4 acc[4][2];
  floatx4 zf = {0.f, 0.f, 0.f, 0.f};
#pragma unroll
  for (int ot = 0; ot < 4; ++ot)
#pragma unroll
    for (int nt = 0; nt < 2; ++nt) acc[ot][nt] = zf;
#pragma unroll
  for (int kc = 0; kc < 16; ++kc) {
    short8 a[4], bfr[2];
#pragma unroll
    for (int ot = 0; ot < 4; ++ot)
      a[ot] = *(const short8*)(WfB + (size_t)(o_w + ot * 16 + li) * (2 * CC) +
                               kc * 32 + q * 8);
    if (kc < 8) {
#pragma unroll
      for (int nt = 0; nt < 2; ++nt)
        bfr[nt] = *(const short8*)(&Pn[nt * 16 + li][kc * 32 + q * 8]);
    } else {
#pragma unroll
      for (int nt = 0; nt < 2; ++nt)
        bfr[nt] = *(const short8*)(xT + (size_t)(n0 + nt * 16 + li) * CC +
                                   (kc - 8) * 32 + q * 8);
    }
#pragma unroll
    for (int ot = 0; ot < 4; ++ot)
#pragma unroll
      for (int nt = 0; nt < 2; ++nt)
        acc[ot][nt] = __builtin_amdgcn_mfma_f32_16x16x32_bf16(a[ot], bfr[nt],
                                                              acc[ot][nt], 0, 0, 0);
  }
  float* ob = out + (size_t)b * CC * NN;
#pragma unroll
  for (int ot = 0; ot < 4; ++ot)
#pragma unroll
    for (int r = 0; r < 4; ++r) {
      int o = o_w + ot * 16 + q * 4 + r;
      float bo = bfv[o];
#pragma unroll
      for (int nt = 0; nt < 2; ++nt)
        ob[(size_t)o * NN + n0 + nt * 16 + li] = acc[ot][nt][r] + bo;
    }
}

// ---------------------------------------------------------------------------
extern "C" void kernel_launch(void* const* d_in, const int* in_sizes, int n_in,
                              void* d_out, int out_size, void* d_ws,
                              size_t ws_size, hipStream_t stream) {
  const float* x_f = (const float*)d_in[0];
  const float* x_b = (const float*)d_in[1];
  const float* Wq  = (const float*)d_in[2];
  const float* bq  = (const float*)d_in[3];
  const float* Wk  = (const float*)d_in[4];
  const float* bk  = (const float*)d_in[5];
  const float* Wv  = (const float*)d_in[6];
  const float* bv  = (const float*)d_in[7];
  const float* Wf  = (const float*)d_in[8];
  const float* bf  = (const float*)d_in[9];
  const float* gm  = (const float*)d_in[10];
  float* out = (float*)d_out;

  // workspace layout — xbT eliminated; peak ~84.4 MB:
  //   [ 0..24) vB       bf16 [12][256][4096]   (fused_in -> attn)
  //   [24..32) xfT      bf16 [4][4096][256]    (fused_in -> final)
  //   [32..80) outs_s   f32  [12][256][4096]   (attn -> final)
  //   [80..83) qT, [83..84) kT, [84..84.41) weights
  char* ws = (char*)d_ws;
  __hip_bfloat16* vB     = (__hip_bfloat16*)ws;                         // 24 MB
  __hip_bfloat16* xfT    = (__hip_bfloat16*)(ws + ((size_t)24 << 20));  //  8 MB
  float*          outs_s = (float*)(ws + ((size_t)32 << 20));           // 48 MB
  __hip_bfloat16* qT     = (__hip_bfloat16*)(ws + ((size_t)80 << 20));  //  3 MB
  __hip_bfloat16* kT     = (__hip_bfloat16*)(ws + ((size_t)83 << 20));  //  1 MB
  __hip_bfloat16* WqB    = (__hip_bfloat16*)(ws + ((size_t)84 << 20));  // 16 KB
  __hip_bfloat16* WkB    = WqB + 8192;                                  // 16 KB
  __hip_bfloat16* WvB    = WkB + 8192;                                  // 128 KB
  __hip_bfloat16* WfB    = WvB + 65536;                                 // 256 KB

  hipLaunchKernelGGL(wconv_kernel, dim3(832), dim3(256), 0, stream,
                     Wq, Wk, Wv, Wf, WqB, WkB, WvB, WfB);
  hipLaunchKernelGGL(fused_in_kernel, dim3(NN / 64, 16), dim3(256), 0, stream,
                     x_b, x_f, WqB, WkB, WvB, bq, bk, bv, qT, kT, vB, xfT);
  hipLaunchKernelGGL(attn_kernel, dim3(768), dim3(256), 0, stream,
                     qT, kT, vB, outs_s);
  hipLaunchKernelGGL(final_kernel, dim3(NN / 32, BB), dim3(256), 0, stream,
                     outs_s, xfT, WfB, bf, gm, out);
}

// Round 11
// 384.320 us; speedup vs baseline: 1.0007x; 1.0007x over previous
//
#include <hip/hip_runtime.h>
#include <hip/hip_bf16.h>

#define BB 4
#define CC 256
#define NN 4096
#define SS 3
#define C8 32
#define L2E 1.4426950408889634f

typedef __attribute__((ext_vector_type(8))) short short8;
typedef __attribute__((ext_vector_type(4))) float floatx4;

static __device__ inline unsigned pack_bf16(float a, float b) {
  union { __hip_bfloat16 h; unsigned short u; } ua, ub;
  ua.h = __float2bfloat16(a);
  ub.h = __float2bfloat16(b);
  return ((unsigned)ub.u << 16) | (unsigned)ua.u;
}

// hardware packed convert: one v_cvt_pk_bf16_f32 (RNE) per pair
static __device__ inline unsigned cvt_pk_bf16(float a, float b) {
  union { __hip_bfloat162 h2; unsigned u; } cv;
  cv.h2 = __float22bfloat162_rn(make_float2(a, b));
  return cv.u;
}

static __device__ inline float fast_exp2(float x) {
#if __has_builtin(__builtin_amdgcn_exp2f)
  return __builtin_amdgcn_exp2f(x);
#else
  return exp2f(x);
#endif
}

// ---------------------------------------------------------------------------
// P0: weight fp32->bf16 convert (832 blocks, ~4us). Must precede fused_in.
// ---------------------------------------------------------------------------
__global__ void __launch_bounds__(256) wconv_kernel(
    const float* __restrict__ Wq, const float* __restrict__ Wk,
    const float* __restrict__ Wv, const float* __restrict__ Wf,
    __hip_bfloat16* __restrict__ WqB, __hip_bfloat16* __restrict__ WkB,
    __hip_bfloat16* __restrict__ WvB, __hip_bfloat16* __restrict__ WfB) {
  int idx = blockIdx.x * 256 + threadIdx.x;
  if (idx < 8192) WqB[idx] = __float2bfloat16(Wq[idx] * L2E);
  else if (idx < 16384) WkB[idx - 8192] = __float2bfloat16(Wk[idx - 8192]);
  else if (idx < 81920) WvB[idx - 16384] = __float2bfloat16(Wv[idx - 16384]);
  else if (idx < 212992) WfB[idx - 81920] = __float2bfloat16(Wf[idx - 81920]);
}

// ---------------------------------------------------------------------------
// F1: fused transpose + projection. Grid (64 n-tiles, 16 z).
// z<12 (x_b plane g=z):  stage 64n x 256c tile -> swizzled bf16 LDS, then
//   V-proj and Q-proj. z>=12 (x_f): stage tile, write xfT, K-proj.
// xbT intermediate eliminated. UNCHANGED from round 10.
// ---------------------------------------------------------------------------
__global__ void __launch_bounds__(256) fused_in_kernel(
    const float* __restrict__ xb, const float* __restrict__ xf,
    const __hip_bfloat16* __restrict__ WqB, const __hip_bfloat16* __restrict__ WkB,
    const __hip_bfloat16* __restrict__ WvB,
    const float* __restrict__ bq, const float* __restrict__ bk,
    const float* __restrict__ bv,
    __hip_bfloat16* __restrict__ qT, __hip_bfloat16* __restrict__ kT,
    __hip_bfloat16* __restrict__ vB, __hip_bfloat16* __restrict__ xfT) {
  __shared__ float ts[64][65];
  __shared__ char xs[64 * 512];  // bf16 [64 n][256 c], 16B-chunk XOR swizzle
  const int z = blockIdx.y;
  const bool isb = (z < 12);
  const int g = isb ? z : z - 12;
  const int n0 = blockIdx.x * 64;
  const int t = threadIdx.x, w = t >> 6, lane = t & 63;
  const int q = lane >> 4, li = lane & 15;
  const float* X = (isb ? xb : xf) + (size_t)g * CC * NN + n0;
  __hip_bfloat16* xout = xfT + (size_t)g * NN * CC + (size_t)n0 * CC;

  // stage: 4 c-chunks of 64: fp32 transpose staging -> packed bf16 tile
  for (int cc = 0; cc < 4; ++cc) {
    const float* Xg = X + (size_t)(cc * 64) * NN;
    for (int idx = t; idx < 64 * 64; idx += 256) {
      int r = idx >> 6, nn = idx & 63;
      ts[r][nn] = Xg[(size_t)r * NN + nn];
    }
    __syncthreads();
    for (int idx = t; idx < 64 * 32; idx += 256) {
      int nn = idx >> 5, pc = idx & 31;  // pc = dword within this c-chunk
      unsigned pv = cvt_pk_bf16(ts[2 * pc][nn], ts[2 * pc + 1][nn]);
      int d = cc * 32 + pc;              // dword index within row, 0..127
      int chunk = (d >> 2) ^ (nn & 7);
      ((unsigned*)(xs + nn * 512 + chunk * 16))[d & 3] = pv;
      if (!isb) ((unsigned*)(xout + (size_t)nn * CC))[d] = pv;
    }
    __syncthreads();
  }

  floatx4 zf = {0.f, 0.f, 0.f, 0.f};
  if (isb) {
    // ---- V projection: wave w owns o-quarter w*64, nt=0..3 over the n-tile
    const int o_w = w * 64;
    __hip_bfloat16* dst = vB + (size_t)g * CC * NN;
    floatx4 acc[4][4];
#pragma unroll
    for (int ot = 0; ot < 4; ++ot)
#pragma unroll
      for (int nt = 0; nt < 4; ++nt) acc[ot][nt] = zf;
#pragma unroll
    for (int kc = 0; kc < 8; ++kc) {
      short8 a[4], bfr[4];
#pragma unroll
      for (int ot = 0; ot < 4; ++ot)
        a[ot] = *(const short8*)(WvB + (size_t)(o_w + ot * 16 + li) * CC + kc * 32 + q * 8);
#pragma unroll
      for (int nt = 0; nt < 4; ++nt) {
        int nn = nt * 16 + li;
        int chunk = (kc * 4 + q) ^ (nn & 7);
        bfr[nt] = *(const short8*)(xs + nn * 512 + chunk * 16);
      }
#pragma unroll
      for (int ot = 0; ot < 4; ++ot)
#pragma unroll
        for (int nt = 0; nt < 4; ++nt)
          acc[ot][nt] = __builtin_amdgcn_mfma_f32_16x16x32_bf16(a[ot], bfr[nt],
                                                                acc[ot][nt], 0, 0, 0);
    }
#pragma unroll
    for (int ot = 0; ot < 4; ++ot) {
#pragma unroll
      for (int r = 0; r < 4; ++r) {
        int o = o_w + ot * 16 + q * 4 + r;
        float bo = bv[o];
#pragma unroll
        for (int nt = 0; nt < 4; ++nt)
          dst[(size_t)o * NN + n0 + nt * 16 + li] =
              __float2bfloat16(acc[ot][nt][r] + bo);
      }
    }
    // ---- Q projection: wave w owns n-sub w*16 (16 rows), 32 outputs
    {
      __hip_bfloat16* qdst = qT + (size_t)g * NN * C8;
      const int nn = w * 16 + li;
      floatx4 acc2[2];
      acc2[0] = zf; acc2[1] = zf;
#pragma unroll
      for (int kc = 0; kc < 8; ++kc) {
        short8 a2[2];
#pragma unroll
        for (int ot = 0; ot < 2; ++ot)
          a2[ot] = *(const short8*)(WqB + (size_t)(ot * 16 + li) * CC + kc * 32 + q * 8);
        int chunk = (kc * 4 + q) ^ (nn & 7);
        short8 bfr = *(const short8*)(xs + nn * 512 + chunk * 16);
#pragma unroll
        for (int ot = 0; ot < 2; ++ot)
          acc2[ot] = __builtin_amdgcn_mfma_f32_16x16x32_bf16(a2[ot], bfr, acc2[ot], 0, 0, 0);
      }
#pragma unroll
      for (int ot = 0; ot < 2; ++ot) {
        float bv0 = bq[ot * 16 + q * 4 + 0] * L2E;
        float bv1 = bq[ot * 16 + q * 4 + 1] * L2E;
        float bv2 = bq[ot * 16 + q * 4 + 2] * L2E;
        float bv3 = bq[ot * 16 + q * 4 + 3] * L2E;
        int n = n0 + nn;
        uint2 pk;
        pk.x = pack_bf16(acc2[ot][0] + bv0, acc2[ot][1] + bv1);
        pk.y = pack_bf16(acc2[ot][2] + bv2, acc2[ot][3] + bv3);
        *(uint2*)(qdst + (size_t)n * C8 + ot * 16 + q * 4) = pk;
      }
    }
  } else {
    // ---- K projection: wave w owns n-sub w*16
    __hip_bfloat16* kdst = kT + (size_t)g * NN * C8;
    const int nn = w * 16 + li;
    floatx4 acc2[2];
    acc2[0] = zf; acc2[1] = zf;
#pragma unroll
    for (int kc = 0; kc < 8; ++kc) {
      short8 a2[2];
#pragma unroll
      for (int ot = 0; ot < 2; ++ot)
        a2[ot] = *(const short8*)(WkB + (size_t)(ot * 16 + li) * CC + kc * 32 + q * 8);
      int chunk = (kc * 4 + q) ^ (nn & 7);
      short8 bfr = *(const short8*)(xs + nn * 512 + chunk * 16);
#pragma unroll
      for (int ot = 0; ot < 2; ++ot)
        acc2[ot] = __builtin_amdgcn_mfma_f32_16x16x32_bf16(a2[ot], bfr, acc2[ot], 0, 0, 0);
    }
#pragma unroll
    for (int ot = 0; ot < 2; ++ot) {
      float bv0 = bk[ot * 16 + q * 4 + 0];
      float bv1 = bk[ot * 16 + q * 4 + 1];
      float bv2 = bk[ot * 16 + q * 4 + 2];
      float bv3 = bk[ot * 16 + q * 4 + 3];
      int n = n0 + nn;
      uint2 pk;
      pk.x = pack_bf16(acc2[ot][0] + bv0, acc2[ot][1] + bv1);
      pk.y = pack_bf16(acc2[ot][2] + bv2, acc2[ot][3] + bv3);
      *(uint2*)(kdst + (size_t)n * C8 + ot * 16 + q * 4) = pk;
    }
  }
}

// ---------------------------------------------------------------------------
// K3: MFMA flash attention — round-9 structure (213us) + J-PHASE STAGGER:
// each block starts its j-loop at offset ((wk*7)&31)*128. All 768 blocks are
// co-resident; without stagger the ~64 blocks sharing a g read the SAME V
// lines simultaneously (c-rows are block-independent) -> L2 slice-camping
// (measured 0.88 TB/s/XCD effective vs ~4.3 ceiling). Stagger spreads
// concurrent reads across the whole 2MB slab (still L2-resident -> FETCH_SIZE
// unchanged). j-order change only permutes fp32 accumulation (P bf16 values
// identical; absmax bit-stable across j-orders in r6/r8). Zero register cost.
// ---------------------------------------------------------------------------
__global__ void __launch_bounds__(256) attn_kernel(
    const __hip_bfloat16* __restrict__ qT, const __hip_bfloat16* __restrict__ kT,
    const __hip_bfloat16* __restrict__ vB, float* __restrict__ outs_s) {
  __shared__ uint4 Ps4[4 * 64 * 8];  // 4 x 8KB P buffers, 16B-chunk XOR swizzle
  __shared__ float lsum[64];
  char* Ps0 = (char*)Ps4;
  const int x_ = blockIdx.x;
  const int wk = (x_ & 7) * 96 + (x_ >> 3);  // contiguous range per XCD
  const int g  = wk >> 6;                    // 0..11 (= s*4+b)
  const int i0 = (wk & 63) << 6;
  const int b  = g & 3;
  const int t  = threadIdx.x;
  const int w  = t >> 6;
  const int lane = t & 63, q = lane >> 4, li = lane & 15;
  const int joff = (wk * 7) & 31;            // per-block j-phase stagger

  if (t < 64) lsum[t] = 0.f;

  short8 qf[4];
#pragma unroll
  for (int it = 0; it < 4; ++it)
    qf[it] = *(const short8*)(qT + ((size_t)g * NN + i0 + it * 16 + li) * C8 + q * 8);

  floatx4 acc[4][4];
  floatx4 zf = {0.f, 0.f, 0.f, 0.f};
#pragma unroll
  for (int ct = 0; ct < 4; ++ct)
#pragma unroll
    for (int it = 0; it < 4; ++it) acc[ct][it] = zf;
  float rsum[4] = {0.f, 0.f, 0.f, 0.f};

  const __hip_bfloat16* kb = kT + (size_t)b * NN * C8;
  const __hip_bfloat16* vb = vB + (size_t)g * CC * NN;
  {
    const int j0 = (joff & 31) << 7;
    short8 k0 = *(const short8*)(kb + (size_t)(j0 + 0 + w * 16 + li) * C8 + q * 8);
    short8 k1 = *(const short8*)(kb + (size_t)(j0 + 64 + w * 16 + li) * C8 + q * 8);
    // fallthrough init below
    // (kf0/kf1 declared after to keep init simple)
    // -- see loop
    // store into loop-carried registers:
    // handled by declaring here:
    #define KF_INIT
    // (clang folds this fine)
    // kf0/kf1:
    // declared next line
    // (kept minimal to avoid structural changes)
    // ---
    // actual declarations:
    // (placed outside the braces)
    goto after_init;
after_init:;
    // move into loop-carried vars
    // (see below)
    // NOTE: simple structure — declare kf0/kf1 here:
    static_assert(true, "");
    // assign:
    // (fall through)
    // ---
    // Using locals declared below:
    // kf0 = k0; kf1 = k1;  (done after declaration)
    // To keep code clean, declare now:
    ;
    // (end init block)
    // ---
    // The declarations:
    // short8 kf0, kf1;  -- declared below, assigned here via lambda-scope trick
    // Simplify: declare before this block instead.
    (void)k0; (void)k1;
  }
  // clean re-do of K init (compiler CSEs the duplicate loads)
  short8 kf0, kf1;
  {
    const int j0 = (joff & 31) << 7;
    kf0 = *(const short8*)(kb + (size_t)(j0 + 0 + w * 16 + li) * C8 + q * 8);
    kf1 = *(const short8*)(kb + (size_t)(j0 + 64 + w * 16 + li) * C8 + q * 8);
  }

  for (int ji = 0; ji < 32; ++ji) {
    const int j0  = ((ji + joff) & 31) << 7;
    const int j0n = ((ji + 1 + joff) & 31) << 7;
    char* PsA = Ps0 + (ji & 1) * 16384;  // pair {0,1} / {2,3} alternates
    char* PsB = PsA + 8192;
    // V frags for subtile A: issue first so L2 latency hides under S/exp work
    short8 vfA[4][2];
#pragma unroll
    for (int ct = 0; ct < 4; ++ct)
#pragma unroll
      for (int kk = 0; kk < 2; ++kk)
        vfA[ct][kk] = *(const short8*)(vb + (size_t)(w * 64 + ct * 16 + li) * NN +
                                       j0 + kk * 32 + q * 8);
    // --- subtile A: S^T strip, exp2, pack, LDS write (stA dies here) ---
    {
      floatx4 stA[4];
#pragma unroll
      for (int it = 0; it < 4; ++it)
        stA[it] = __builtin_amdgcn_mfma_f32_16x16x32_bf16(kf0, qf[it], zf, 0, 0, 0);
      kf0 = *(const short8*)(kb + (size_t)(j0n + w * 16 + li) * C8 + q * 8);
      uint2 pk[4];
#pragma unroll
      for (int it = 0; it < 4; ++it) {
        float e0 = fast_exp2(stA[it][0]), e1 = fast_exp2(stA[it][1]);
        float e2 = fast_exp2(stA[it][2]), e3 = fast_exp2(stA[it][3]);
        rsum[it] += (e0 + e1) + (e2 + e3);
        pk[it].x = cvt_pk_bf16(e0, e1);
        pk[it].y = cvt_pk_bf16(e2, e3);
      }
#pragma unroll
      for (int it = 0; it < 4; ++it) {
        int row = it * 16 + li;
        int chunk = (w * 2 + (q >> 1)) ^ (row & 7);
        *(uint2*)(PsA + row * 128 + chunk * 16 + (q & 1) * 8) = pk[it];
      }
    }
    // --- subtile B: S^T strip, exp2, pack, LDS write ---
    {
      floatx4 stB[4];
#pragma unroll
      for (int it = 0; it < 4; ++it)
        stB[it] = __builtin_amdgcn_mfma_f32_16x16x32_bf16(kf1, qf[it], zf, 0, 0, 0);
      kf1 = *(const short8*)(kb + (size_t)(j0n + 64 + w * 16 + li) * C8 + q * 8);
      uint2 pk[4];
#pragma unroll
      for (int it = 0; it < 4; ++it) {
        float e0 = fast_exp2(stB[it][0]), e1 = fast_exp2(stB[it][1]);
        float e2 = fast_exp2(stB[it][2]), e3 = fast_exp2(stB[it][3]);
        rsum[it] += (e0 + e1) + (e2 + e3);
        pk[it].x = cvt_pk_bf16(e0, e1);
        pk[it].y = cvt_pk_bf16(e2, e3);
      }
#pragma unroll
      for (int it = 0; it < 4; ++it) {
        int row = it * 16 + li;
        int chunk = (w * 2 + (q >> 1)) ^ (row & 7);
        *(uint2*)(PsB + row * 128 + chunk * 16 + (q & 1) * 8) = pk[it];
      }
    }
    __syncthreads();  // one barrier per 128 j; alternating pairs make reads safe
    // --- PV subtile A (vfA dies here) ---
    __builtin_amdgcn_s_setprio(1);
#pragma unroll
    for (int kk = 0; kk < 2; ++kk) {
      short8 pf[4];
#pragma unroll
      for (int it = 0; it < 4; ++it) {
        int row = it * 16 + li;
        int chunk = (kk * 4 + q) ^ (row & 7);
        pf[it] = *(const short8*)(PsA + row * 128 + chunk * 16);
      }
#pragma unroll
      for (int ct = 0; ct < 4; ++ct)
#pragma unroll
        for (int it = 0; it < 4; ++it)
          acc[ct][it] = __builtin_amdgcn_mfma_f32_16x16x32_bf16(
              vfA[ct][kk], pf[it], acc[ct][it], 0, 0, 0);
    }
    __builtin_amdgcn_s_setprio(0);
    // V frags for subtile B (vfA dead -> regs reuse)
    short8 vfB[4][2];
#pragma unroll
    for (int ct = 0; ct < 4; ++ct)
#pragma unroll
      for (int kk = 0; kk < 2; ++kk)
        vfB[ct][kk] = *(const short8*)(vb + (size_t)(w * 64 + ct * 16 + li) * NN +
                                       j0 + 64 + kk * 32 + q * 8);
    // --- PV subtile B ---
    __builtin_amdgcn_s_setprio(1);
#pragma unroll
    for (int kk = 0; kk < 2; ++kk) {
      short8 pf[4];
#pragma unroll
      for (int it = 0; it < 4; ++it) {
        int row = it * 16 + li;
        int chunk = (kk * 4 + q) ^ (row & 7);
        pf[it] = *(const short8*)(PsB + row * 128 + chunk * 16);
      }
#pragma unroll
      for (int ct = 0; ct < 4; ++ct)
#pragma unroll
        for (int it = 0; it < 4; ++it)
          acc[ct][it] = __builtin_amdgcn_mfma_f32_16x16x32_bf16(
              vfB[ct][kk], pf[it], acc[ct][it], 0, 0, 0);
    }
    __builtin_amdgcn_s_setprio(0);
  }
#pragma unroll
  for (int it = 0; it < 4; ++it) {
    float v = rsum[it];
    v += __shfl_xor(v, 16, 64);
    v += __shfl_xor(v, 32, 64);
    if (lane < 16) atomicAdd(&lsum[it * 16 + li], v);
  }
  __syncthreads();
  float inv[4];
#pragma unroll
  for (int it = 0; it < 4; ++it) inv[it] = 1.0f / lsum[it * 16 + li];
  float* ob = outs_s + (size_t)g * CC * NN + i0;
#pragma unroll
  for (int ct = 0; ct < 4; ++ct)
#pragma unroll
    for (int it = 0; it < 4; ++it)
#pragma unroll
      for (int r = 0; r < 4; ++r) {
        int c = w * 64 + ct * 16 + q * 4 + r;
        ob[(size_t)c * NN + it * 16 + li] = acc[ct][it][r] * inv[it];
      }
}

// ---------------------------------------------------------------------------
// G3: final projection with T2 fused (3-way s-sum + gamma + transpose staged
// through LDS), n-tile 32, grid (128, 4). UNCHANGED from round 10.
// ---------------------------------------------------------------------------
__global__ void __launch_bounds__(256) final_kernel(
    const float* __restrict__ outs_s, const __hip_bfloat16* __restrict__ xfT,
    const __hip_bfloat16* __restrict__ WfB, const float* __restrict__ bfv,
    const float* __restrict__ gp, float* __restrict__ out) {
  __shared__ float ts[64][33];
  __shared__ __hip_bfloat16 Pn[32][280];
  const int b = blockIdx.y, n0 = blockIdx.x * 32;
  const int t = threadIdx.x, w = t >> 6, lane = t & 63;
  const int q = lane >> 4, li = lane & 15;
  const float sc = gp[0];
  for (int cc = 0; cc < 4; ++cc) {
    const int c0 = cc * 64;
    const float* X0 = outs_s + ((size_t)(0 + b) * CC + c0) * NN + n0;
    const float* X1 = outs_s + ((size_t)(4 + b) * CC + c0) * NN + n0;
    const float* X2 = outs_s + ((size_t)(8 + b) * CC + c0) * NN + n0;
    for (int idx = t; idx < 64 * 32; idx += 256) {
      int r = idx >> 5, col = idx & 31;
      size_t off = (size_t)r * NN + col;
      ts[r][col] = X0[off] + X1[off] + X2[off];
    }
    __syncthreads();
    for (int idx = t; idx < 32 * 32; idx += 256) {
      int n = idx >> 5, pc = idx & 31;
      ((unsigned*)&Pn[n][c0])[pc] =
          pack_bf16(ts[2 * pc][n] * sc, ts[2 * pc + 1][n] * sc);
    }
    __syncthreads();
  }
  const __hip_bfloat16* xT = xfT + (size_t)b * NN * CC;
  const int o_w = w * 64;
  floatx4 acc[4][2];
  floatx4 zf = {0.f, 0.f, 0.f, 0.f};
#pragma unroll
  for (int ot = 0; ot < 4; ++ot)
#pragma unroll
    for (int nt = 0; nt < 2; ++nt) acc[ot][nt] = zf;
#pragma unroll
  for (int kc = 0; kc < 16; ++kc) {
    short8 a[4], bfr[2];
#pragma unroll
    for (int ot = 0; ot < 4; ++ot)
      a[ot] = *(const short8*)(WfB + (size_t)(o_w + ot * 16 + li) * (2 * CC) +
                               kc * 32 + q * 8);
    if (kc < 8) {
#pragma unroll
      for (int nt = 0; nt < 2; ++nt)
        bfr[nt] = *(const short8*)(&Pn[nt * 16 + li][kc * 32 + q * 8]);
    } else {
#pragma unroll
      for (int nt = 0; nt < 2; ++nt)
        bfr[nt] = *(const short8*)(xT + (size_t)(n0 + nt * 16 + li) * CC +
                                   (kc - 8) * 32 + q * 8);
    }
#pragma unroll
    for (int ot = 0; ot < 4; ++ot)
#pragma unroll
      for (int nt = 0; nt < 2; ++nt)
        acc[ot][nt] = __builtin_amdgcn_mfma_f32_16x16x32_bf16(a[ot], bfr[nt],
                                                              acc[ot][nt], 0, 0, 0);
  }
  float* ob = out + (size_t)b * CC * NN;
#pragma unroll
  for (int ot = 0; ot < 4; ++ot)
#pragma unroll
    for (int r = 0; r < 4; ++r) {
      int o = o_w + ot * 16 + q * 4 + r;
      float bo = bfv[o];
#pragma unroll
      for (int nt = 0; nt < 2; ++nt)
        ob[(size_t)o * NN + n0 + nt * 16 + li] = acc[ot][nt][r] + bo;
    }
}

// ---------------------------------------------------------------------------
extern "C" void kernel_launch(void* const* d_in, const int* in_sizes, int n_in,
                              void* d_out, int out_size, void* d_ws,
                              size_t ws_size, hipStream_t stream) {
  const float* x_f = (const float*)d_in[0];
  const float* x_b = (const float*)d_in[1];
  const float* Wq  = (const float*)d_in[2];
  const float* bq  = (const float*)d_in[3];
  const float* Wk  = (const float*)d_in[4];
  const float* bk  = (const float*)d_in[5];
  const float* Wv  = (const float*)d_in[6];
  const float* bv  = (const float*)d_in[7];
  const float* Wf  = (const float*)d_in[8];
  const float* bf  = (const float*)d_in[9];
  const float* gm  = (const float*)d_in[10];
  float* out = (float*)d_out;

  // workspace layout — xbT eliminated; peak ~84.4 MB:
  //   [ 0..24) vB       bf16 [12][256][4096]   (fused_in -> attn)
  //   [24..32) xfT      bf16 [4][4096][256]    (fused_in -> final)
  //   [32..80) outs_s   f32  [12][256][4096]   (attn -> final)
  //   [80..83) qT, [83..84) kT, [84..84.41) weights
  char* ws = (char*)d_ws;
  __hip_bfloat16* vB     = (__hip_bfloat16*)ws;                         // 24 MB
  __hip_bfloat16* xfT    = (__hip_bfloat16*)(ws + ((size_t)24 << 20));  //  8 MB
  float*          outs_s = (float*)(ws + ((size_t)32 << 20));           // 48 MB
  __hip_bfloat16* qT     = (__hip_bfloat16*)(ws + ((size_t)80 << 20));  //  3 MB
  __hip_bfloat16* kT     = (__hip_bfloat16*)(ws + ((size_t)83 << 20));  //  1 MB
  __hip_bfloat16* WqB    = (__hip_bfloat16*)(ws + ((size_t)84 << 20));  // 16 KB
  __hip_bfloat16* WkB    = WqB + 8192;                                  // 16 KB
  __hip_bfloat16* WvB    = WkB + 8192;                                  // 128 KB
  __hip_bfloat16* WfB    = WvB + 65536;                                 // 256 KB

  hipLaunchKernelGGL(wconv_kernel, dim3(832), dim3(256), 0, stream,
                     Wq, Wk, Wv, Wf, WqB, WkB, WvB, WfB);
  hipLaunchKernelGGL(fused_in_kernel, dim3(NN / 64, 16), dim3(256), 0, stream,
                     x_b, x_f, WqB, WkB, WvB, bq, bk, bv, qT, kT, vB, xfT);
  hipLaunchKernelGGL(attn_kernel, dim3(768), dim3(256), 0, stream,
                     qT, kT, vB, outs_s);
  hipLaunchKernelGGL(final_kernel, dim3(NN / 32, BB), dim3(256), 0, stream,
                     outs_s, xfT, WfB, bf, gm, out);
}